// Round 3
// baseline (1333.118 us; speedup 1.0000x reference)
//
#include <hip/hip_runtime.h>
#include <math.h>

#define N_SAMPLES 524288
#define A_ACT 8
#define D_DIM 64
#define E_DIM 32
#define LOG2PI_F 1.8378770664093453f

#define SORT_THREADS 256
#define CHUNK 4096
#define NBLK (N_SAMPLES / CHUNK)      // 128
#define HIST_SIZE (A_ACT * NBLK)      // 1024
#define SCAN_PER (HIST_SIZE / 256)    // 4

// ---------------- Kernel 1: per-block histogram ----------------
__global__ __launch_bounds__(SORT_THREADS) void hist_kernel(
    const int* __restrict__ idx, int* __restrict__ hist) {
  __shared__ int cnt[A_ACT];
  int t = threadIdx.x;
  if (t < A_ACT) cnt[t] = 0;
  __syncthreads();
  int base = blockIdx.x * CHUNK;
  for (int j = t; j < CHUNK; j += SORT_THREADS) {
    atomicAdd(&cnt[idx[base + j]], 1);
  }
  __syncthreads();
  if (t < A_ACT) hist[t * NBLK + blockIdx.x] = cnt[t];
}

// ---------------- Kernel 2: exclusive scan of hist (1 block) ----------------
__global__ __launch_bounds__(256) void scan_kernel(int* __restrict__ hist) {
  __shared__ int sums[256];
  int t = threadIdx.x;
  int vals[SCAN_PER];
  int s = 0;
#pragma unroll
  for (int k = 0; k < SCAN_PER; ++k) {
    vals[k] = hist[t * SCAN_PER + k];
    s += vals[k];
  }
  sums[t] = s;
  __syncthreads();
  for (int off = 1; off < 256; off <<= 1) {
    int v = (t >= off) ? sums[t - off] : 0;
    __syncthreads();
    sums[t] += v;
    __syncthreads();
  }
  int prefix = (t == 0) ? 0 : sums[t - 1];
#pragma unroll
  for (int k = 0; k < SCAN_PER; ++k) {
    int v = vals[k];
    hist[t * SCAN_PER + k] = prefix;
    prefix += v;
  }
}

// ---------------- Kernel 3: stable scatter (builds p and inv) ----------------
__global__ __launch_bounds__(SORT_THREADS) void scatter_kernel(
    const int* __restrict__ idx, const int* __restrict__ offs,
    int* __restrict__ p, int* __restrict__ inv) {
  __shared__ int base[A_ACT];
  __shared__ int wcnt[4][A_ACT];
  int t = threadIdx.x;
  int wave = t >> 6;
  int lane = t & 63;
  if (t < A_ACT) base[t] = offs[t * NBLK + blockIdx.x];
  __syncthreads();
  int cstart = blockIdx.x * CHUNK;
  for (int pass = 0; pass < CHUNK / SORT_THREADS; ++pass) {
    int i = cstart + pass * SORT_THREADS + t;
    int a = idx[i];
    unsigned long long mymask = 0ULL;
#pragma unroll
    for (int aa = 0; aa < A_ACT; ++aa) {
      unsigned long long m = __ballot(a == aa);
      if (aa == a) mymask = m;
      if (lane == 0) wcnt[wave][aa] = __popcll(m);
    }
    unsigned long long below = (1ULL << lane) - 1ULL;
    int inwave = __popcll(mymask & below);
    __syncthreads();
    int wprefix = 0;
#pragma unroll
    for (int w = 0; w < 4; ++w)
      if (w < wave) wprefix += wcnt[w][a];
    int r = base[a] + wprefix + inwave;
    p[r] = i;
    inv[i] = r;
    __syncthreads();
    if (t < A_ACT) {
      int tot = 0;
#pragma unroll
      for (int w = 0; w < 4; ++w) tot += wcnt[w][t];
      base[t] += tot;
    }
    __syncthreads();
  }
}

// ---------------- Kernel 4: fused matvec + rsample + logprob ----------------
// One actor per block; 256 sorted rows per block.
// Phase 1: coalesced staging of state rows into LDS (XOR-swizzled chunks).
// Phase 2: 4 rows x 8 e register tile fed entirely from LDS.
#define TILE_ROWS 256
#define MAIN_THREADS 256
#define MAIN_BLOCKS (N_SAMPLES / TILE_ROWS + A_ACT)

__global__ __launch_bounds__(MAIN_THREADS, 2) void main_kernel(
    const float* __restrict__ state, const float* __restrict__ W,
    const float* __restrict__ bias, const float* __restrict__ lstd,
    const float* __restrict__ eps, const int* __restrict__ p,
    const int* __restrict__ inv, const int* __restrict__ offs,
    float* __restrict__ out_action, float* __restrict__ out_lp) {
  __shared__ float sW[D_DIM * E_DIM];          // 8 KB  [d][e]
  __shared__ float sS[TILE_ROWS * D_DIM];      // 64 KB, chunk-swizzled
  __shared__ int s_p[TILE_ROWS];
  __shared__ int s_d[TILE_ROWS];

  int t = threadIdx.x;
  int bid = blockIdx.x;

  // Map block -> (actor, row chunk): each block serves exactly one actor.
  int a = -1, kbase = 0, kend = 0;
  int acc_b = 0;
#pragma unroll
  for (int aa = 0; aa < A_ACT; ++aa) {
    int start = offs[aa * NBLK];
    int end = (aa == A_ACT - 1) ? N_SAMPLES : offs[(aa + 1) * NBLK];
    int cnt = end - start;
    int nc = (cnt + TILE_ROWS - 1) / TILE_ROWS;
    if (a < 0 && bid < acc_b + nc) {
      a = aa;
      int chunk = bid - acc_b;
      kbase = start + chunk * TILE_ROWS;
      kend = min(end, kbase + TILE_ROWS);
    }
    acc_b += nc;
  }
  if (a < 0) return;  // uniform across block
  int nrows = kend - kbase;

  // Load permutation rows (clamped) and W.
  {
    int kc = kbase + min(t, nrows - 1);
    s_p[t] = p[kc];
    s_d[t] = inv[kc];
    const float4* wg = (const float4*)(W + (size_t)a * (D_DIM * E_DIM));
    ((float4*)sW)[t] = wg[t];
    ((float4*)sW)[t + 256] = wg[t + 256];
  }
  __syncthreads();

  // Stage state rows: 16 lanes per row -> one contiguous 256B read per row.
  // Chunk x (16B) of row stored at chunk x ^ ((row>>2)&7).
  {
    int u = t >> 4;   // 0..15
    int x = t & 15;   // chunk within row
#pragma unroll
    for (int it = 0; it < 16; ++it) {
      int row = it * 16 + u;
      int m = s_p[row];
      float4 v = *(const float4*)(state + (size_t)m * D_DIM + x * 4);
      int xs = x ^ ((row >> 2) & 7);
      *(float4*)(&sS[row * D_DIM + xs * 4]) = v;
    }
  }
  __syncthreads();

  int rg = t >> 2;       // row group 0..63 (4 rows each)
  int es = t & 3;        // e-slice 0..3
  int e0 = es * 8;
  int r0 = rg * 4;
  int key = rg & 7;      // == ((r0+r)>>2)&7 for r=0..3

  float facc[4][8];
#pragma unroll
  for (int r = 0; r < 4; ++r)
#pragma unroll
    for (int j = 0; j < 8; ++j) facc[r][j] = 0.f;

  const float4* sSv = (const float4*)sS;  // [row*16 + chunk]
#pragma unroll
  for (int c = 0; c < D_DIM / 4; ++c) {
    int cs = c ^ key;
    float4 sv0 = sSv[(r0 + 0) * 16 + cs];
    float4 sv1 = sSv[(r0 + 1) * 16 + cs];
    float4 sv2 = sSv[(r0 + 2) * 16 + cs];
    float4 sv3 = sSv[(r0 + 3) * 16 + cs];
    const float sarr0[4] = {sv0.x, sv0.y, sv0.z, sv0.w};
    const float sarr1[4] = {sv1.x, sv1.y, sv1.z, sv1.w};
    const float sarr2[4] = {sv2.x, sv2.y, sv2.z, sv2.w};
    const float sarr3[4] = {sv3.x, sv3.y, sv3.z, sv3.w};
#pragma unroll
    for (int dd = 0; dd < 4; ++dd) {
      int d = c * 4 + dd;
      float4 w0 = *(const float4*)(&sW[d * E_DIM + e0]);
      float4 w1 = *(const float4*)(&sW[d * E_DIM + e0 + 4]);
      float wv[8] = {w0.x, w0.y, w0.z, w0.w, w1.x, w1.y, w1.z, w1.w};
#pragma unroll
      for (int j = 0; j < 8; ++j) {
        facc[0][j] = fmaf(sarr0[dd], wv[j], facc[0][j]);
        facc[1][j] = fmaf(sarr1[dd], wv[j], facc[1][j]);
        facc[2][j] = fmaf(sarr2[dd], wv[j], facc[2][j]);
        facc[3][j] = fmaf(sarr3[dd], wv[j], facc[3][j]);
      }
    }
  }

  // Epilogue: bias, std, action, log-prob.
  float4 bv0 = *(const float4*)(bias + a * E_DIM + e0);
  float4 bv1 = *(const float4*)(bias + a * E_DIM + e0 + 4);
  float4 lv0 = *(const float4*)(lstd + a * E_DIM + e0);
  float4 lv1 = *(const float4*)(lstd + a * E_DIM + e0 + 4);
  float bva[8] = {bv0.x, bv0.y, bv0.z, bv0.w, bv1.x, bv1.y, bv1.z, bv1.w};
  float lsa[8] = {lv0.x, lv0.y, lv0.z, lv0.w, lv1.x, lv1.y, lv1.z, lv1.w};
  float sda[8];
#pragma unroll
  for (int j = 0; j < 8; ++j) sda[j] = expf(lsa[j]);

#pragma unroll
  for (int r = 0; r < 4; ++r) {
    int rl = r0 + r;
    bool valid = (rl < nrows);
    int rlc = valid ? rl : (nrows - 1);
    int kr = kbase + rlc;
    int dest = s_d[rlc];
    float4 ev0 = *(const float4*)(eps + (size_t)kr * E_DIM + e0);
    float4 ev1 = *(const float4*)(eps + (size_t)kr * E_DIM + e0 + 4);
    float ep[8] = {ev0.x, ev0.y, ev0.z, ev0.w, ev1.x, ev1.y, ev1.z, ev1.w};
    float o[8];
    float part = 0.f;
#pragma unroll
    for (int j = 0; j < 8; ++j) {
      float mean = facc[r][j] + bva[j];
      o[j] = fmaf(sda[j], ep[j], mean);
      part += fmaf(-0.5f * ep[j], ep[j], -lsa[j]);
    }
    part += __shfl_xor(part, 1, 64);
    part += __shfl_xor(part, 2, 64);
    if (valid) {
      float* op = out_action + (size_t)dest * E_DIM + e0;
      *(float4*)(op) = make_float4(o[0], o[1], o[2], o[3]);
      *(float4*)(op + 4) = make_float4(o[4], o[5], o[6], o[7]);
      if (es == 0) out_lp[dest] = part - 16.0f * LOG2PI_F;
    }
  }
}

extern "C" void kernel_launch(void* const* d_in, const int* in_sizes, int n_in,
                              void* d_out, int out_size, void* d_ws, size_t ws_size,
                              hipStream_t stream) {
  const float* state = (const float*)d_in[0];
  const float* W     = (const float*)d_in[1];
  const float* b     = (const float*)d_in[2];
  const float* ls    = (const float*)d_in[3];
  const float* eps   = (const float*)d_in[4];
  const int*   idx   = (const int*)d_in[5];

  float* out_action = (float*)d_out;                              // [N, E]
  float* out_lp     = (float*)d_out + (size_t)N_SAMPLES * E_DIM;  // [N]

  int* p    = (int*)d_ws;
  int* inv  = p + N_SAMPLES;
  int* hist = inv + N_SAMPLES;

  hipLaunchKernelGGL(hist_kernel, dim3(NBLK), dim3(SORT_THREADS), 0, stream,
                     idx, hist);
  hipLaunchKernelGGL(scan_kernel, dim3(1), dim3(256), 0, stream, hist);
  hipLaunchKernelGGL(scatter_kernel, dim3(NBLK), dim3(SORT_THREADS), 0, stream,
                     idx, hist, p, inv);
  hipLaunchKernelGGL(main_kernel, dim3(MAIN_BLOCKS), dim3(MAIN_THREADS),
                     0, stream, state, W, b, ls, eps, p, inv, hist,
                     out_action, out_lp);
}

// Round 4
// 164.343 us; speedup vs baseline: 8.1118x; 8.1118x over previous
//
#include <hip/hip_runtime.h>
#include <math.h>

#define N_SAMPLES 524288
#define A_ACT 8
#define D_DIM 64
#define E_DIM 32
#define LOG2PI_F 1.8378770664093453f

#define SORT_THREADS 256
#define CHUNK 4096
#define NBLK (N_SAMPLES / CHUNK)      // 128
#define HIST_SIZE (A_ACT * NBLK)      // 1024
#define SCAN_PER (HIST_SIZE / 256)    // 4

// ---------------- Kernel 1: per-block histogram ----------------
__global__ __launch_bounds__(SORT_THREADS) void hist_kernel(
    const int* __restrict__ idx, int* __restrict__ hist) {
  __shared__ int cnt[A_ACT];
  int t = threadIdx.x;
  if (t < A_ACT) cnt[t] = 0;
  __syncthreads();
  int base = blockIdx.x * CHUNK;
  for (int j = t; j < CHUNK; j += SORT_THREADS) {
    atomicAdd(&cnt[idx[base + j]], 1);
  }
  __syncthreads();
  if (t < A_ACT) hist[t * NBLK + blockIdx.x] = cnt[t];
}

// ---------------- Kernel 2: exclusive scan of hist (1 block) ----------------
__global__ __launch_bounds__(256) void scan_kernel(int* __restrict__ hist) {
  __shared__ int sums[256];
  int t = threadIdx.x;
  int vals[SCAN_PER];
  int s = 0;
#pragma unroll
  for (int k = 0; k < SCAN_PER; ++k) {
    vals[k] = hist[t * SCAN_PER + k];
    s += vals[k];
  }
  sums[t] = s;
  __syncthreads();
  for (int off = 1; off < 256; off <<= 1) {
    int v = (t >= off) ? sums[t - off] : 0;
    __syncthreads();
    sums[t] += v;
    __syncthreads();
  }
  int prefix = (t == 0) ? 0 : sums[t - 1];
#pragma unroll
  for (int k = 0; k < SCAN_PER; ++k) {
    int v = vals[k];
    hist[t * SCAN_PER + k] = prefix;
    prefix += v;
  }
}

// ---------------- Kernel 3: stable scatter (builds p and inv) ----------------
__global__ __launch_bounds__(SORT_THREADS) void scatter_kernel(
    const int* __restrict__ idx, const int* __restrict__ offs,
    int* __restrict__ p, int* __restrict__ inv) {
  __shared__ int base[A_ACT];
  __shared__ int wcnt[4][A_ACT];
  int t = threadIdx.x;
  int wave = t >> 6;
  int lane = t & 63;
  if (t < A_ACT) base[t] = offs[t * NBLK + blockIdx.x];
  __syncthreads();
  int cstart = blockIdx.x * CHUNK;
  for (int pass = 0; pass < CHUNK / SORT_THREADS; ++pass) {
    int i = cstart + pass * SORT_THREADS + t;
    int a = idx[i];
    unsigned long long mymask = 0ULL;
#pragma unroll
    for (int aa = 0; aa < A_ACT; ++aa) {
      unsigned long long m = __ballot(a == aa);
      if (aa == a) mymask = m;
      if (lane == 0) wcnt[wave][aa] = __popcll(m);
    }
    unsigned long long below = (1ULL << lane) - 1ULL;
    int inwave = __popcll(mymask & below);
    __syncthreads();
    int wprefix = 0;
#pragma unroll
    for (int w = 0; w < 4; ++w)
      if (w < wave) wprefix += wcnt[w][a];
    int r = base[a] + wprefix + inwave;
    p[r] = i;
    inv[i] = r;
    __syncthreads();
    if (t < A_ACT) {
      int tot = 0;
#pragma unroll
      for (int w = 0; w < 4; ++w) tot += wcnt[w][t];
      base[t] += tot;
    }
    __syncthreads();
  }
}

// ---------------- Kernel 4: fused matvec + rsample + logprob ----------------
// One actor per block; 128 sorted rows per block.
// Phase 1: coalesced staging of state rows into LDS (XOR-swizzled chunks).
// Phase 2: 4 rows x 4 e register tile (16 acc) fed from LDS. No spill.
#define TILE_ROWS 128
#define MAIN_THREADS 256
#define MAIN_BLOCKS (N_SAMPLES / TILE_ROWS + A_ACT)

__global__ __launch_bounds__(MAIN_THREADS) void main_kernel(
    const float* __restrict__ state, const float* __restrict__ W,
    const float* __restrict__ bias, const float* __restrict__ lstd,
    const float* __restrict__ eps, const int* __restrict__ p,
    const int* __restrict__ inv, const int* __restrict__ offs,
    float* __restrict__ out_action, float* __restrict__ out_lp) {
  __shared__ float sW[D_DIM * E_DIM];          // 8 KB  [d][e]
  __shared__ float sS[TILE_ROWS * D_DIM];      // 32 KB, chunk-swizzled
  __shared__ int s_d[TILE_ROWS];

  int t = threadIdx.x;
  int bid = blockIdx.x;

  // Map block -> (actor, row chunk): each block serves exactly one actor.
  int a = -1, kbase = 0, kend = 0;
  int acc_b = 0;
#pragma unroll
  for (int aa = 0; aa < A_ACT; ++aa) {
    int start = offs[aa * NBLK];
    int end = (aa == A_ACT - 1) ? N_SAMPLES : offs[(aa + 1) * NBLK];
    int cnt = end - start;
    int nc = (cnt + TILE_ROWS - 1) / TILE_ROWS;
    if (a < 0 && bid < acc_b + nc) {
      a = aa;
      int chunk = bid - acc_b;
      kbase = start + chunk * TILE_ROWS;
      kend = min(end, kbase + TILE_ROWS);
    }
    acc_b += nc;
  }
  if (a < 0) return;  // uniform across block
  int nrows = kend - kbase;

  // Load dest permutation (clamped) and W.
  if (t < TILE_ROWS) {
    int kc = kbase + min(t, nrows - 1);
    s_d[t] = inv[kc];
  }
  {
    const float4* wg = (const float4*)(W + (size_t)a * (D_DIM * E_DIM));
    ((float4*)sW)[t] = wg[t];
    ((float4*)sW)[t + 256] = wg[t + 256];
  }

  // Stage state rows: 16 lanes per row -> one contiguous 256B read per row.
  // Chunk x (16B) of row stored at x ^ ((row>>2)&7).
  {
    int u = t >> 4;   // 0..15 row-slot
    int x = t & 15;   // chunk within row
#pragma unroll
    for (int it = 0; it < TILE_ROWS / 16; ++it) {   // 8 iters
      int row = it * 16 + u;
      int kc = kbase + min(row, nrows - 1);
      int m = p[kc];
      float4 v = *(const float4*)(state + (size_t)m * D_DIM + x * 4);
      int xs = x ^ ((row >> 2) & 7);
      *(float4*)(&sS[row * D_DIM + xs * 4]) = v;
    }
  }
  __syncthreads();

  int rg = t >> 3;       // row group 0..31 (4 rows each)
  int es = t & 7;        // e-slice 0..7
  int e0 = es * 4;
  int r0 = rg * 4;
  int key = rg & 7;      // == ((r0+r)>>2)&7 for r=0..3

  float facc[4][4];
#pragma unroll
  for (int r = 0; r < 4; ++r)
#pragma unroll
    for (int j = 0; j < 4; ++j) facc[r][j] = 0.f;

  const float4* sSv = (const float4*)sS;  // [row*16 + chunk]
#pragma unroll
  for (int c = 0; c < D_DIM / 4; ++c) {
    int cs = c ^ key;
    float4 sv0 = sSv[(r0 + 0) * 16 + cs];
    float4 sv1 = sSv[(r0 + 1) * 16 + cs];
    float4 sv2 = sSv[(r0 + 2) * 16 + cs];
    float4 sv3 = sSv[(r0 + 3) * 16 + cs];
    const float sa0[4] = {sv0.x, sv0.y, sv0.z, sv0.w};
    const float sa1[4] = {sv1.x, sv1.y, sv1.z, sv1.w};
    const float sa2[4] = {sv2.x, sv2.y, sv2.z, sv2.w};
    const float sa3[4] = {sv3.x, sv3.y, sv3.z, sv3.w};
#pragma unroll
    for (int dd = 0; dd < 4; ++dd) {
      int d = c * 4 + dd;
      float4 w = *(const float4*)(&sW[d * E_DIM + e0]);
      const float wv[4] = {w.x, w.y, w.z, w.w};
#pragma unroll
      for (int j = 0; j < 4; ++j) {
        facc[0][j] = fmaf(sa0[dd], wv[j], facc[0][j]);
        facc[1][j] = fmaf(sa1[dd], wv[j], facc[1][j]);
        facc[2][j] = fmaf(sa2[dd], wv[j], facc[2][j]);
        facc[3][j] = fmaf(sa3[dd], wv[j], facc[3][j]);
      }
    }
  }

  // Epilogue: bias, std, action, log-prob. One row at a time (low reg use).
  float4 bv = *(const float4*)(bias + a * E_DIM + e0);
  float4 lv = *(const float4*)(lstd + a * E_DIM + e0);
  const float bva[4] = {bv.x, bv.y, bv.z, bv.w};
  const float lsa[4] = {lv.x, lv.y, lv.z, lv.w};
  float sda[4];
#pragma unroll
  for (int j = 0; j < 4; ++j) sda[j] = expf(lsa[j]);
  float lsum = lsa[0] + lsa[1] + lsa[2] + lsa[3];

#pragma unroll
  for (int r = 0; r < 4; ++r) {
    int rl = r0 + r;
    bool valid = (rl < nrows);
    int rlc = valid ? rl : (nrows - 1);
    int kr = kbase + rlc;
    int dest = s_d[rlc];
    float4 ev = *(const float4*)(eps + (size_t)kr * E_DIM + e0);
    const float ep[4] = {ev.x, ev.y, ev.z, ev.w};
    float o[4];
    float part = -lsum;
#pragma unroll
    for (int j = 0; j < 4; ++j) {
      float mean = facc[r][j] + bva[j];
      o[j] = fmaf(sda[j], ep[j], mean);
      part = fmaf(-0.5f * ep[j], ep[j], part);
    }
    part += __shfl_xor(part, 1, 64);
    part += __shfl_xor(part, 2, 64);
    part += __shfl_xor(part, 4, 64);
    if (valid) {
      float* op = out_action + (size_t)dest * E_DIM + e0;
      *(float4*)op = make_float4(o[0], o[1], o[2], o[3]);
      if (es == 0) out_lp[dest] = part - 16.0f * LOG2PI_F;
    }
  }
}

extern "C" void kernel_launch(void* const* d_in, const int* in_sizes, int n_in,
                              void* d_out, int out_size, void* d_ws, size_t ws_size,
                              hipStream_t stream) {
  const float* state = (const float*)d_in[0];
  const float* W     = (const float*)d_in[1];
  const float* b     = (const float*)d_in[2];
  const float* ls    = (const float*)d_in[3];
  const float* eps   = (const float*)d_in[4];
  const int*   idx   = (const int*)d_in[5];

  float* out_action = (float*)d_out;                              // [N, E]
  float* out_lp     = (float*)d_out + (size_t)N_SAMPLES * E_DIM;  // [N]

  int* p    = (int*)d_ws;
  int* inv  = p + N_SAMPLES;
  int* hist = inv + N_SAMPLES;

  hipLaunchKernelGGL(hist_kernel, dim3(NBLK), dim3(SORT_THREADS), 0, stream,
                     idx, hist);
  hipLaunchKernelGGL(scan_kernel, dim3(1), dim3(256), 0, stream, hist);
  hipLaunchKernelGGL(scatter_kernel, dim3(NBLK), dim3(SORT_THREADS), 0, stream,
                     idx, hist, p, inv);
  hipLaunchKernelGGL(main_kernel, dim3(MAIN_BLOCKS), dim3(MAIN_THREADS),
                     0, stream, state, W, b, ls, eps, p, inv, hist,
                     out_action, out_lp);
}

// Round 5
// 90.090 us; speedup vs baseline: 14.7976x; 1.8242x over previous
//
#include <hip/hip_runtime.h>
#include <math.h>

#define N_SAMPLES 524288
#define A_ACT 8
#define D_DIM 64
#define E_DIM 32
#define LOG2PI_F 1.8378770664093453f

#define SORT_THREADS 256
#define CHUNK 4096
#define NBLK (N_SAMPLES / CHUNK)      // 128
#define HIST_SIZE (A_ACT * NBLK)      // 1024
#define SCAN_PER (HIST_SIZE / 256)    // 4

// ---------------- Kernel 1: per-block histogram ----------------
__global__ __launch_bounds__(SORT_THREADS) void hist_kernel(
    const int* __restrict__ idx, int* __restrict__ hist) {
  __shared__ int cnt[A_ACT];
  int t = threadIdx.x;
  if (t < A_ACT) cnt[t] = 0;
  __syncthreads();
  int base = blockIdx.x * CHUNK;
  for (int j = t; j < CHUNK; j += SORT_THREADS) {
    atomicAdd(&cnt[idx[base + j]], 1);
  }
  __syncthreads();
  if (t < A_ACT) hist[t * NBLK + blockIdx.x] = cnt[t];
}

// ---------------- Kernel 2: exclusive scan of hist (1 block) ----------------
__global__ __launch_bounds__(256) void scan_kernel(int* __restrict__ hist) {
  __shared__ int sums[256];
  int t = threadIdx.x;
  int vals[SCAN_PER];
  int s = 0;
#pragma unroll
  for (int k = 0; k < SCAN_PER; ++k) {
    vals[k] = hist[t * SCAN_PER + k];
    s += vals[k];
  }
  sums[t] = s;
  __syncthreads();
  for (int off = 1; off < 256; off <<= 1) {
    int v = (t >= off) ? sums[t - off] : 0;
    __syncthreads();
    sums[t] += v;
    __syncthreads();
  }
  int prefix = (t == 0) ? 0 : sums[t - 1];
#pragma unroll
  for (int k = 0; k < SCAN_PER; ++k) {
    int v = vals[k];
    hist[t * SCAN_PER + k] = prefix;
    prefix += v;
  }
}

// ---------------- Kernel 3: stable scatter (builds p and inv) ----------------
__global__ __launch_bounds__(SORT_THREADS) void scatter_kernel(
    const int* __restrict__ idx, const int* __restrict__ offs,
    int* __restrict__ p, int* __restrict__ inv) {
  __shared__ int base[A_ACT];
  __shared__ int wcnt[4][A_ACT];
  int t = threadIdx.x;
  int wave = t >> 6;
  int lane = t & 63;
  if (t < A_ACT) base[t] = offs[t * NBLK + blockIdx.x];
  __syncthreads();
  int cstart = blockIdx.x * CHUNK;
  for (int pass = 0; pass < CHUNK / SORT_THREADS; ++pass) {
    int i = cstart + pass * SORT_THREADS + t;
    int a = idx[i];
    unsigned long long mymask = 0ULL;
#pragma unroll
    for (int aa = 0; aa < A_ACT; ++aa) {
      unsigned long long m = __ballot(a == aa);
      if (aa == a) mymask = m;
      if (lane == 0) wcnt[wave][aa] = __popcll(m);
    }
    unsigned long long below = (1ULL << lane) - 1ULL;
    int inwave = __popcll(mymask & below);
    __syncthreads();
    int wprefix = 0;
#pragma unroll
    for (int w = 0; w < 4; ++w)
      if (w < wave) wprefix += wcnt[w][a];
    int r = base[a] + wprefix + inwave;
    p[r] = i;
    inv[i] = r;
    __syncthreads();
    if (t < A_ACT) {
      int tot = 0;
#pragma unroll
      for (int w = 0; w < 4; ++w) tot += wcnt[w][t];
      base[t] += tot;
    }
    __syncthreads();
  }
}

// ---------------- Kernel 4: fused matvec + rsample + logprob ----------------
// One actor per block; 128 sorted rows per block.
// Phase 1: coalesced staging of state rows into LDS (XOR-swizzled chunks).
// Phase 2: 4 rows x 4 e register tile (16 acc) fed from LDS.
// LDS exactly 40 KB -> 4 blocks/CU; launch_bounds(256,4) -> <=128 VGPR.
#define TILE_ROWS 128
#define MAIN_THREADS 256
#define MAIN_BLOCKS (N_SAMPLES / TILE_ROWS + A_ACT)

__global__ __launch_bounds__(MAIN_THREADS, 4) void main_kernel(
    const float* __restrict__ state, const float* __restrict__ W,
    const float* __restrict__ bias, const float* __restrict__ lstd,
    const float* __restrict__ eps, const int* __restrict__ p,
    const int* __restrict__ inv, const int* __restrict__ offs,
    float* __restrict__ out_action, float* __restrict__ out_lp) {
  __shared__ float sW[D_DIM * E_DIM];          // 8 KB  [d][e]
  __shared__ float sS[TILE_ROWS * D_DIM];      // 32 KB, chunk-swizzled

  int t = threadIdx.x;
  int bid = blockIdx.x;

  // Map block -> (actor, row chunk): each block serves exactly one actor.
  int a = -1, kbase = 0, kend = 0;
  int acc_b = 0;
#pragma unroll
  for (int aa = 0; aa < A_ACT; ++aa) {
    int start = offs[aa * NBLK];
    int end = (aa == A_ACT - 1) ? N_SAMPLES : offs[(aa + 1) * NBLK];
    int cnt = end - start;
    int nc = (cnt + TILE_ROWS - 1) / TILE_ROWS;
    if (a < 0 && bid < acc_b + nc) {
      a = aa;
      int chunk = bid - acc_b;
      kbase = start + chunk * TILE_ROWS;
      kend = min(end, kbase + TILE_ROWS);
    }
    acc_b += nc;
  }
  if (a < 0) return;  // uniform across block
  int nrows = kend - kbase;

  // Stage W[a]: 2048 floats = 512 float4, 2 per thread.
  {
    const float4* wg = (const float4*)(W + (size_t)a * (D_DIM * E_DIM));
    ((float4*)sW)[t] = wg[t];
    ((float4*)sW)[t + 256] = wg[t + 256];
  }

  // Stage state rows: 16 lanes per row -> one contiguous 256B read per row.
  // Chunk x (16B) of row stored at x ^ ((row>>2)&7).
  {
    int u = t >> 4;   // 0..15 row-slot
    int x = t & 15;   // chunk within row
#pragma unroll
    for (int it = 0; it < TILE_ROWS / 16; ++it) {   // 8 iters
      int row = it * 16 + u;
      int kc = kbase + min(row, nrows - 1);
      int m = p[kc];
      float4 v = *(const float4*)(state + (size_t)m * D_DIM + x * 4);
      int xs = x ^ ((row >> 2) & 7);
      *(float4*)(&sS[row * D_DIM + xs * 4]) = v;
    }
  }
  __syncthreads();

  int rg = t >> 3;       // row group 0..31 (4 rows each)
  int es = t & 7;        // e-slice 0..7
  int e0 = es * 4;
  int r0 = rg * 4;
  int key = rg & 7;      // == ((r0+r)>>2)&7 for r=0..3

  float facc[4][4];
#pragma unroll
  for (int r = 0; r < 4; ++r)
#pragma unroll
    for (int j = 0; j < 4; ++j) facc[r][j] = 0.f;

  const float4* sSv = (const float4*)sS;  // [row*16 + chunk]
#pragma unroll 4
  for (int c = 0; c < D_DIM / 4; ++c) {
    int cs = c ^ key;
    float4 sv0 = sSv[(r0 + 0) * 16 + cs];
    float4 sv1 = sSv[(r0 + 1) * 16 + cs];
    float4 sv2 = sSv[(r0 + 2) * 16 + cs];
    float4 sv3 = sSv[(r0 + 3) * 16 + cs];
    const float sa0[4] = {sv0.x, sv0.y, sv0.z, sv0.w};
    const float sa1[4] = {sv1.x, sv1.y, sv1.z, sv1.w};
    const float sa2[4] = {sv2.x, sv2.y, sv2.z, sv2.w};
    const float sa3[4] = {sv3.x, sv3.y, sv3.z, sv3.w};
#pragma unroll
    for (int dd = 0; dd < 4; ++dd) {
      int d = c * 4 + dd;
      float4 w = *(const float4*)(&sW[d * E_DIM + e0]);
      const float wv[4] = {w.x, w.y, w.z, w.w};
#pragma unroll
      for (int j = 0; j < 4; ++j) {
        facc[0][j] = fmaf(sa0[dd], wv[j], facc[0][j]);
        facc[1][j] = fmaf(sa1[dd], wv[j], facc[1][j]);
        facc[2][j] = fmaf(sa2[dd], wv[j], facc[2][j]);
        facc[3][j] = fmaf(sa3[dd], wv[j], facc[3][j]);
      }
    }
  }

  // Epilogue: bias, std, action, log-prob. One row at a time (low reg use).
  float4 bv = *(const float4*)(bias + a * E_DIM + e0);
  float4 lv = *(const float4*)(lstd + a * E_DIM + e0);
  const float bva[4] = {bv.x, bv.y, bv.z, bv.w};
  const float lsa[4] = {lv.x, lv.y, lv.z, lv.w};
  float sda[4];
#pragma unroll
  for (int j = 0; j < 4; ++j) sda[j] = expf(lsa[j]);
  float lsum = lsa[0] + lsa[1] + lsa[2] + lsa[3];

#pragma unroll
  for (int r = 0; r < 4; ++r) {
    int rl = r0 + r;
    bool valid = (rl < nrows);
    int rlc = valid ? rl : (nrows - 1);
    int kr = kbase + rlc;
    int dest = inv[kr];
    float4 ev = *(const float4*)(eps + (size_t)kr * E_DIM + e0);
    const float ep[4] = {ev.x, ev.y, ev.z, ev.w};
    float o[4];
    float part = -lsum;
#pragma unroll
    for (int j = 0; j < 4; ++j) {
      float mean = facc[r][j] + bva[j];
      o[j] = fmaf(sda[j], ep[j], mean);
      part = fmaf(-0.5f * ep[j], ep[j], part);
    }
    part += __shfl_xor(part, 1, 64);
    part += __shfl_xor(part, 2, 64);
    part += __shfl_xor(part, 4, 64);
    if (valid) {
      float* op = out_action + (size_t)dest * E_DIM + e0;
      *(float4*)op = make_float4(o[0], o[1], o[2], o[3]);
      if (es == 0) out_lp[dest] = part - 16.0f * LOG2PI_F;
    }
  }
}

extern "C" void kernel_launch(void* const* d_in, const int* in_sizes, int n_in,
                              void* d_out, int out_size, void* d_ws, size_t ws_size,
                              hipStream_t stream) {
  const float* state = (const float*)d_in[0];
  const float* W     = (const float*)d_in[1];
  const float* b     = (const float*)d_in[2];
  const float* ls    = (const float*)d_in[3];
  const float* eps   = (const float*)d_in[4];
  const int*   idx   = (const int*)d_in[5];

  float* out_action = (float*)d_out;                              // [N, E]
  float* out_lp     = (float*)d_out + (size_t)N_SAMPLES * E_DIM;  // [N]

  int* p    = (int*)d_ws;
  int* inv  = p + N_SAMPLES;
  int* hist = inv + N_SAMPLES;

  hipLaunchKernelGGL(hist_kernel, dim3(NBLK), dim3(SORT_THREADS), 0, stream,
                     idx, hist);
  hipLaunchKernelGGL(scan_kernel, dim3(1), dim3(256), 0, stream, hist);
  hipLaunchKernelGGL(scatter_kernel, dim3(NBLK), dim3(SORT_THREADS), 0, stream,
                     idx, hist, p, inv);
  hipLaunchKernelGGL(main_kernel, dim3(MAIN_BLOCKS), dim3(MAIN_THREADS),
                     0, stream, state, W, b, ls, eps, p, inv, hist,
                     out_action, out_lp);
}